// Round 17
// baseline (149.944 us; speedup 1.0000x reference)
//
#include <hip/hip_runtime.h>
#include <hip/hip_bf16.h>
#include <cmath>

#define NS 512   // n_stocks (attention sequence length)
#define NT 512   // tau (batch)
#define DIM 64
#define HD 32

typedef __attribute__((ext_vector_type(8))) short short8;    // 8 bf16 = 4 VGPR
typedef __attribute__((ext_vector_type(16))) float f32x16;   // MFMA 32x32 acc

union FragU { unsigned w[4]; short8 f; };

// 2^x. Builtin/libm form lowers to v_exp_f32 but stays visible to the
// scheduler (inline-asm version cost +23 us in rounds 4/5 — latency opaque).
#if __has_builtin(__builtin_amdgcn_exp2f)
#define EXP2F __builtin_amdgcn_exp2f
#else
#define EXP2F exp2f
#endif

// bf16 RNE rounding, bit-trick form (bit-identical to __float2bfloat16 for
// finite values; inputs are finite). Result in HIGH 16 bits.
// NOTE round 8: inline-asm v_cvt_pk_bf16_f32 produced NaN on gfx950 — never
// hand-write that instruction.
__device__ __forceinline__ unsigned bfround(float x) {
  unsigned u = __float_as_uint(x);
  return u + 0x7fffu + ((u >> 16) & 1u);
}
// pack two fp32 -> {hi16=bf16(hi), lo16=bf16(lo)} via one v_perm_b32
__device__ __forceinline__ unsigned pk2(float lo, float hi) {
  return __builtin_amdgcn_perm(bfround(hi), bfround(lo), 0x07060302u);
}
__device__ __forceinline__ float lo_f(unsigned w) { return __uint_as_float(w << 16); }
__device__ __forceinline__ float hi_f(unsigned w) { return __uint_as_float(w & 0xffff0000u); }
__device__ __forceinline__ short8 ldg8(const __hip_bfloat16* p) {
  return *reinterpret_cast<const short8*>(p);
}

// v_permlane32_swap_b32: a' = [a.lo | b.lo], b' = [a.hi | b.hi]
__device__ __forceinline__ void pl32swap(unsigned& a, unsigned& b) {
  asm volatile("v_permlane32_swap_b32 %0, %1" : "+v"(a), "+v"(b));
}

// Repack a 32x32 C-frag (col=l31, row=(r&3)+8*(r>>2)+4*hi) into two A/B-frags
// along k (o1: k=0..15, o2: k=16..31). Validated rounds 2-16.
__device__ __forceinline__ void repack(const float* p, short8& o1, short8& o2) {
  unsigned pk[8];
  #pragma unroll
  for (int j = 0; j < 8; ++j) pk[j] = pk2(p[2 * j], p[2 * j + 1]);
  pl32swap(pk[0], pk[2]);
  pl32swap(pk[1], pk[3]);
  pl32swap(pk[4], pk[6]);
  pl32swap(pk[5], pk[7]);
  FragU a1, a2;
  a1.w[0] = pk[0]; a1.w[1] = pk[1]; a1.w[2] = pk[2]; a1.w[3] = pk[3];
  a2.w[0] = pk[4]; a2.w[1] = pk[5]; a2.w[2] = pk[6]; a2.w[3] = pk[7];
  o1 = a1.f; o2 = a2.f;
}

// ---------------- K0: convert all weights fp32 -> bf16 in ws ----------------
// layout: Wqkv @0 (12288) | Wo @12288 (4096) | W1 @16384 (16384) | W2 @32768 (16384)
__global__ void k_cvt(const float* __restrict__ Wqkv, const float* __restrict__ Wo,
                      const float* __restrict__ W1, const float* __restrict__ W2,
                      __hip_bfloat16* __restrict__ dst) {
  int i = blockIdx.x * 256 + threadIdx.x;  // 49152 total
  float v;
  if (i < 12288) v = Wqkv[i];
  else if (i < 16384) v = Wo[i - 12288];
  else if (i < 32768) v = W1[i - 16384];
  else v = W2[i - 32768];
  *reinterpret_cast<unsigned short*>(dst + i) = (unsigned short)(bfround(v) >> 16);
}

// ---------------- K1: MFMA QKV projection + MFMA attention -----------------
// Round-16 kernel (validated 96.5us; XCD swizzle keeps the (t,0)/(t,1) pair on
// one XCD so the shared x-read L2-hits). ROUND 17 single change: softmax
// row-sum moved to the MFMA pipe — lacc = mfma(ones, P-frag, lacc) reuses the
// already-packed P fragments and replaces 480 VALU tree-adds + a shfl_xor.
// All C rows of (ones x P) equal sum_k P[k][q], so lacc[0] is lsum directly.
__global__ __launch_bounds__(512, 4) void k_attn(
    const float* __restrict__ x, const __hip_bfloat16* __restrict__ Wb,
    const float* __restrict__ bqkv, __hip_bfloat16* __restrict__ ctx) {
  __shared__ char smem[65536];
  const int bid = blockIdx.x;
  const int t = (bid & 7) | ((bid >> 4) << 3);
  const int h = (bid >> 3) & 1;
  const int tid = threadIdx.x;
  const int l = tid & 63, wv = tid >> 6, hi = l >> 5, l31 = l & 31;

  // ---- x fragments: lane row = wv*64+rt*32+l31, dims st*16+hi*8+(0..7) ----
  short8 xf[2][4];
  #pragma unroll
  for (int rt = 0; rt < 2; ++rt) {
    int row = wv * 64 + rt * 32 + l31;
    const float* xr = x + ((size_t)row * NT + t) * DIM + hi * 8;
    #pragma unroll
    for (int st = 0; st < 4; ++st) {
      float4 f0 = *reinterpret_cast<const float4*>(xr + st * 16);
      float4 f1 = *reinterpret_cast<const float4*>(xr + st * 16 + 4);
      FragU fu;
      fu.w[0] = pk2(f0.x, f0.y); fu.w[1] = pk2(f0.z, f0.w);
      fu.w[2] = pk2(f1.x, f1.y); fu.w[3] = pk2(f1.z, f1.w);
      xf[rt][st] = fu.f;
    }
  }

  // ---- K proj (transposed: C rows = kd, cols = stock) -> row-major Ksm ----
  {
    short8 wkb[4];
    #pragma unroll
    for (int st = 0; st < 4; ++st)
      wkb[st] = ldg8(Wb + (size_t)(64 + h * 32 + l31) * 64 + st * 16 + hi * 8);
    #pragma unroll
    for (int rt = 0; rt < 2; ++rt) {
      f32x16 ka = {};
      #pragma unroll
      for (int st = 0; st < 4; ++st)
        ka = __builtin_amdgcn_mfma_f32_32x32x16_bf16(wkb[st], xf[rt][st], ka, 0, 0, 0);
      int stock = wv * 64 + rt * 32 + l31;
      char* kb = smem + stock * 64 + (hi << 3);
      #pragma unroll
      for (int rq = 0; rq < 4; ++rq) {  // regs 4rq..4rq+3 -> kd = 8rq+4hi+(0..3)
        uint2 d2 = make_uint2(pk2(ka[4 * rq + 0], ka[4 * rq + 1]),
                              pk2(ka[4 * rq + 2], ka[4 * rq + 3]));
        *reinterpret_cast<uint2*>(kb + ((rq ^ ((stock >> 1) & 3)) << 4)) = d2;
      }
    }
  }

  // ---- V proj -> Vt[vd][key] (bias folded at store) ----
  {
    short8 wvb[4];
    #pragma unroll
    for (int st = 0; st < 4; ++st)
      wvb[st] = ldg8(Wb + (size_t)(128 + h * 32 + l31) * 64 + st * 16 + hi * 8);
    #pragma unroll
    for (int rt = 0; rt < 2; ++rt) {
      f32x16 va = {};
      #pragma unroll
      for (int st = 0; st < 4; ++st)
        va = __builtin_amdgcn_mfma_f32_32x32x16_bf16(xf[rt][st], wvb[st], va, 0, 0, 0);
      #pragma unroll
      for (int g = 0; g < 4; ++g) {
        int kb = wv * 64 + rt * 32 + g * 8 + hi * 4;
        uint2 d2 = make_uint2(pk2(va[4 * g + 0], va[4 * g + 1]),
                              pk2(va[4 * g + 2], va[4 * g + 3]));
        *reinterpret_cast<uint2*>(
            smem + 32768 + l31 * 1024 + (((kb >> 3) ^ (l31 & 7)) << 4) + ((kb & 7) << 1)) = d2;
      }
    }
  }

  // ---- Q^T proj -> qfrag (registers); scale = 1/sqrt(32) * log2(e) ----
  short8 qfrag[2][2];
  {
    short8 wqa[4];
    #pragma unroll
    for (int st = 0; st < 4; ++st)
      wqa[st] = ldg8(Wb + (size_t)(h * 32 + l31) * 64 + st * 16 + hi * 8);
    float bqv[16];
    #pragma unroll
    for (int r = 0; r < 16; ++r)
      bqv[r] = bqkv[h * 32 + (r & 3) + 8 * (r >> 2) + 4 * hi];
    #pragma unroll
    for (int rt = 0; rt < 2; ++rt) {
      f32x16 qa = {};
      #pragma unroll
      for (int st = 0; st < 4; ++st)
        qa = __builtin_amdgcn_mfma_f32_32x32x16_bf16(wqa[st], xf[rt][st], qa, 0, 0, 0);
      float p[16];
      #pragma unroll
      for (int r = 0; r < 16; ++r) p[r] = (qa[r] + bqv[r]) * 0.25503488921708395f;
      repack(p, qfrag[rt][0], qfrag[rt][1]);
    }
  }

  float bvv[16];  // V-bias (vd = (r&3)+8*(r>>2)+4*hi)
  #pragma unroll
  for (int r = 0; r < 16; ++r)
    bvv[r] = bqkv[128 + h * 32 + (r & 3) + 8 * (r >> 2) + 4 * hi];

  // A-fragment of all-ones (bf16 1.0 = 0x3F80): every C row = colsum of B
  short8 ones8;
  {
    FragU fu;
    fu.w[0] = 0x3F803F80u; fu.w[1] = 0x3F803F80u;
    fu.w[2] = 0x3F803F80u; fu.w[3] = 0x3F803F80u;
    ones8 = fu.f;
  }

  __syncthreads();

  // ---- attention main loop over 16 key tiles of 32 ----
  f32x16 oacc[2], lacc[2];
  #pragma unroll
  for (int i = 0; i < 16; ++i) {
    oacc[0][i] = 0.f; oacc[1][i] = 0.f;
    lacc[0][i] = 0.f; lacc[1][i] = 0.f;
  }

  #pragma clang loop unroll(disable)
  for (int kt = 0; kt < 16; ++kt) {
    short8 kfrag[2], vfrag[2];
    int row = kt * 32 + l31;
    #pragma unroll
    for (int dc = 0; dc < 2; ++dc)
      kfrag[dc] = *reinterpret_cast<const short8*>(
          smem + row * 64 + ((((dc << 1) | hi) ^ ((row >> 1) & 3)) << 4));
    #pragma unroll
    for (int c = 0; c < 2; ++c) {
      int ck = kt * 4 + (c << 1) + hi;
      vfrag[c] = *reinterpret_cast<const short8*>(
          smem + 32768 + l31 * 1024 + ((ck ^ (l31 & 7)) << 4));
    }
    #pragma unroll
    for (int sb = 0; sb < 2; ++sb) {
      f32x16 sC = {};
      sC = __builtin_amdgcn_mfma_f32_32x32x16_bf16(kfrag[0], qfrag[sb][0], sC, 0, 0, 0);
      sC = __builtin_amdgcn_mfma_f32_32x32x16_bf16(kfrag[1], qfrag[sb][1], sC, 0, 0, 0);
      float p[16];
      #pragma unroll
      for (int r = 0; r < 16; ++r) p[r] = EXP2F(sC[r]);
      short8 a1, a2;
      repack(p, a1, a2);
      // PV swapped: C[row=vd][col=query] -> 1/l lane-local
      oacc[sb] = __builtin_amdgcn_mfma_f32_32x32x16_bf16(vfrag[0], a1, oacc[sb], 0, 0, 0);
      oacc[sb] = __builtin_amdgcn_mfma_f32_32x32x16_bf16(vfrag[1], a2, oacc[sb], 0, 0, 0);
      // row-sum on the MFMA pipe: lacc rows all = sum_k P[k][query]
      lacc[sb] = __builtin_amdgcn_mfma_f32_32x32x16_bf16(ones8, a1, lacc[sb], 0, 0, 0);
      lacc[sb] = __builtin_amdgcn_mfma_f32_32x32x16_bf16(ones8, a2, lacc[sb], 0, 0, 0);
    }
  }

  // ---- normalize (lane-local, lacc[0] = full lsum) + V-bias + stores ----
  #pragma unroll
  for (int sb = 0; sb < 2; ++sb) {
    float inv = 1.f / lacc[sb][0];
    int q = wv * 64 + sb * 32 + l31;
    __hip_bfloat16* cb = ctx + ((size_t)t * 512 + q) * 64 + h * 32;
    #pragma unroll
    for (int g = 0; g < 4; ++g) {  // regs 4g..4g+3 -> vd = 8g+4hi+(0..3)
      uint2 d2 = make_uint2(
          pk2(fmaf(oacc[sb][4 * g + 0], inv, bvv[4 * g + 0]),
              fmaf(oacc[sb][4 * g + 1], inv, bvv[4 * g + 1])),
          pk2(fmaf(oacc[sb][4 * g + 2], inv, bvv[4 * g + 2]),
              fmaf(oacc[sb][4 * g + 3], inv, bvv[4 * g + 3])));
      *reinterpret_cast<uint2*>(cb + 8 * g + 4 * hi) = d2;
    }
  }
}

// ---------------- K2: MFMA Wo + LN1 + MFMA FFN + LN2 ----------------
// One block per t, 512 thr = 8 waves. EXACT round-11-passing version
// (weights LDS-staged, one barrier after weight writes).
__global__ __launch_bounds__(512, 2) void k_tail(
    const __hip_bfloat16* __restrict__ ctx, const float* __restrict__ x,
    const __hip_bfloat16* __restrict__ Wob,
    const float* __restrict__ bo, const float* __restrict__ g1,
    const float* __restrict__ be1, const __hip_bfloat16* __restrict__ W1b,
    const float* __restrict__ bf1, const __hip_bfloat16* __restrict__ W2b,
    const float* __restrict__ bf2, const float* __restrict__ g2,
    const float* __restrict__ be2, float* __restrict__ out) {
  __shared__ char sm[133632];
  float* ps = reinterpret_cast<float*>(sm + 131072);
  const int t = blockIdx.x;
  const int tid = threadIdx.x;
  const int l = tid & 63, wv = tid >> 6, hi = l >> 5, l31 = l & 31;

  // ---- issue weight staging loads (latency hidden under phase 1) ----
  short8 wst[8];
  {
    const short8* w1p = reinterpret_cast<const short8*>(W1b);
    const short8* w2p = reinterpret_cast<const short8*>(W2b);
    #pragma unroll
    for (int j = 0; j < 4; ++j) wst[j] = w1p[tid + 512 * j];
    #pragma unroll
    for (int j = 0; j < 4; ++j) wst[4 + j] = w2p[tid + 512 * j];
  }

  // ---- stage ctx row + params ----
  {
    const short8* cp = reinterpret_cast<const short8*>(ctx + ((size_t)t * 512 + tid) * 64);
    #pragma unroll
    for (int c = 0; c < 8; ++c)
      *reinterpret_cast<short8*>(sm + tid * 128 + ((c ^ (tid & 7)) << 4)) = cp[c];
  }
  for (int i = tid; i < 640; i += 512) {
    float v;
    if (i < 64) v = g1[i];
    else if (i < 128) v = be1[i - 64];
    else if (i < 192) v = bo[i - 128];
    else if (i < 256) v = bf2[i - 192];
    else if (i < 320) v = g2[i - 256];
    else if (i < 384) v = be2[i - 320];
    else v = bf1[i - 384];
    ps[i] = v;
  }

  // ---- phase 1: aout^T = Wo @ ctx^T, scatter into R1 (wave-private) ----
  {
    short8 cb[2][4];
    #pragma unroll
    for (int stl = 0; stl < 2; ++stl) {
      int lr = wv * 64 + stl * 32 + l31;
      #pragma unroll
      for (int st = 0; st < 4; ++st)
        cb[stl][st] = *reinterpret_cast<const short8*>(
            sm + lr * 128 + ((((st << 1) | hi) ^ (lr & 7)) << 4));
    }
    #pragma unroll
    for (int dt = 0; dt < 2; ++dt) {
      short8 wa[4];
      #pragma unroll
      for (int st = 0; st < 4; ++st)
        wa[st] = ldg8(Wob + (size_t)(dt * 32 + l31) * 64 + st * 16 + hi * 8);
      #pragma unroll
      for (int stl = 0; stl < 2; ++stl) {
        f32x16 a = {};
        #pragma unroll
        for (int st = 0; st < 4; ++st)
          a = __builtin_amdgcn_mfma_f32_32x32x16_bf16(wa[st], cb[stl][st], a, 0, 0, 0);
        int lr = wv * 64 + stl * 32 + l31;
        #pragma unroll
        for (int q = 0; q < 4; ++q) {  // regs 4q..4q+3 -> d = dt*32+8q+4hi+(0..3)
          uint2 d2 = make_uint2(pk2(a[4 * q + 0], a[4 * q + 1]),
                                pk2(a[4 * q + 2], a[4 * q + 3]));
          *reinterpret_cast<uint2*>(
              sm + lr * 128 + (((dt * 4 + q) ^ (lr & 7)) << 4) + (hi << 3)) = d2;
        }
      }
    }
  }

  // ---- write staged weights to LDS (swizzled), then the ONE barrier ----
  {
    #pragma unroll
    for (int j = 0; j < 4; ++j) {
      int g = tid + 512 * j;  // W1 [256][64]: row=g>>3, chunk=g&7
      *reinterpret_cast<short8*>(
          sm + 65536 + (g >> 3) * 128 + (((g & 7) ^ ((g >> 3) & 7)) << 4)) = wst[j];
    }
    #pragma unroll
    for (int j = 0; j < 4; ++j) {
      int g = tid + 512 * j;  // W2 [64][256]: row=g>>5, chunk=g&31
      *reinterpret_cast<short8*>(
          sm + 98304 + (g >> 5) * 512 + (((g & 31) ^ ((g >> 5) & 7)) << 4)) = wst[4 + j];
    }
  }
  __syncthreads();

  // ---- phase 2: y = LN1(x + aout + bo); y -> R1 rows + packed regs ----
  unsigned ypk[32];
  {
    float ao[64];
    #pragma unroll
    for (int c = 0; c < 8; ++c) {
      FragU fu;
      fu.f = *reinterpret_cast<const short8*>(sm + tid * 128 + ((c ^ (tid & 7)) << 4));
      #pragma unroll
      for (int u = 0; u < 4; ++u) {
        ao[c * 8 + 2 * u]     = lo_f(fu.w[u]);
        ao[c * 8 + 2 * u + 1] = hi_f(fu.w[u]);
      }
    }
    float y[64];
    const float4* xp = reinterpret_cast<const float4*>(x + ((size_t)tid * NT + t) * DIM);
    #pragma unroll
    for (int i = 0; i < 16; ++i) {
      float4 v = xp[i];
      y[4*i+0] = v.x + ao[4*i+0] + ps[128 + 4*i+0];
      y[4*i+1] = v.y + ao[4*i+1] + ps[128 + 4*i+1];
      y[4*i+2] = v.z + ao[4*i+2] + ps[128 + 4*i+2];
      y[4*i+3] = v.w + ao[4*i+3] + ps[128 + 4*i+3];
    }
    float m0 = 0.f, m1 = 0.f, m2 = 0.f, m3 = 0.f;
    #pragma unroll
    for (int j = 0; j < 16; ++j) {
      m0 += y[4*j+0]; m1 += y[4*j+1]; m2 += y[4*j+2]; m3 += y[4*j+3];
    }
    float mu = ((m0 + m1) + (m2 + m3)) * (1.f / 64.f);
    float v0 = 0.f, v1 = 0.f, v2 = 0.f, v3 = 0.f;
    #pragma unroll
    for (int j = 0; j < 16; ++j) {
      float t0 = y[4*j+0] - mu, t1 = y[4*j+1] - mu;
      float t2 = y[4*j+2] - mu, t3 = y[4*j+3] - mu;
      v0 = fmaf(t0, t0, v0); v1 = fmaf(t1, t1, v1);
      v2 = fmaf(t2, t2, v2); v3 = fmaf(t3, t3, v3);
    }
    float var = ((v0 + v1) + (v2 + v3)) * (1.f / 64.f);
    float rs = rsqrtf(var + 1e-5f);
    #pragma unroll
    for (int d = 0; d < 64; ++d) y[d] = (y[d] - mu) * rs * ps[d] + ps[64 + d];
    #pragma unroll
    for (int c = 0; c < 8; ++c) {
      FragU fu;
      #pragma unroll
      for (int u = 0; u < 4; ++u) {
        fu.w[u] = pk2(y[c*8 + 2*u], y[c*8 + 2*u + 1]);
        ypk[4 * c + u] = fu.w[u];
      }
      *reinterpret_cast<short8*>(sm + tid * 128 + ((c ^ (tid & 7)) << 4)) = fu.f;
    }
  }

  // ---- phase 3: FFN, jt-outer (weights once, from LDS); z^T -> R1 ----
  {
    short8 yb[2][4];
    #pragma unroll
    for (int stl = 0; stl < 2; ++stl) {
      int lr = wv * 64 + stl * 32 + l31;
      #pragma unroll
      for (int st = 0; st < 4; ++st)
        yb[stl][st] = *reinterpret_cast<const short8*>(
            sm + lr * 128 + ((((st << 1) | hi) ^ (lr & 7)) << 4));
    }
    f32x16 zacc[2][2];
    #pragma unroll
    for (int i = 0; i < 16; ++i) {
      zacc[0][0][i] = 0.f; zacc[0][1][i] = 0.f; zacc[1][0][i] = 0.f; zacc[1][1][i] = 0.f;
    }
    #pragma clang loop unroll_count(2)
    for (int jt = 0; jt < 8; ++jt) {
      short8 w1a[4];
      #pragma unroll
      for (int st = 0; st < 4; ++st) {
        int row = jt * 32 + l31, c1 = (st << 1) | hi;
        w1a[st] = *reinterpret_cast<const short8*>(
            sm + 65536 + row * 128 + ((c1 ^ (row & 7)) << 4));
      }
      short8 w2f[2][2];
      #pragma unroll
      for (int dt = 0; dt < 2; ++dt)
        #pragma unroll
        for (int ks = 0; ks < 2; ++ks) {
          int row = dt * 32 + l31, c2 = jt * 4 + ks * 2 + hi;
          w2f[dt][ks] = *reinterpret_cast<const short8*>(
              sm + 98304 + row * 512 + ((c2 ^ (row & 7)) << 4));
        }
      float b1v[16];
      #pragma unroll
      for (int r = 0; r < 16; ++r)
        b1v[r] = ps[384 + jt * 32 + (r & 3) + 8 * (r >> 2) + 4 * hi];
      #pragma unroll
      for (int stl = 0; stl < 2; ++stl) {
        f32x16 ha = {};
        #pragma unroll
        for (int st = 0; st < 4; ++st)
          ha = __builtin_amdgcn_mfma_f32_32x32x16_bf16(w1a[st], yb[stl][st], ha, 0, 0, 0);
        float p[16];
        #pragma unroll
        for (int r = 0; r < 16; ++r) p[r] = fmaxf(ha[r] + b1v[r], 0.f);
        short8 b1, b2;
        repack(p, b1, b2);
        zacc[0][stl] = __builtin_amdgcn_mfma_f32_32x32x16_bf16(w2f[0][0], b1, zacc[0][stl], 0, 0, 0);
        zacc[0][stl] = __builtin_amdgcn_mfma_f32_32x32x16_bf16(w2f[0][1], b2, zacc[0][stl], 0, 0, 0);
        zacc[1][stl] = __builtin_amdgcn_mfma_f32_32x32x16_bf16(w2f[1][0], b1, zacc[1][stl], 0, 0, 0);
        zacc[1][stl] = __builtin_amdgcn_mfma_f32_32x32x16_bf16(w2f[1][1], b2, zacc[1][stl], 0, 0, 0);
      }
    }
    #pragma unroll
    for (int dt = 0; dt < 2; ++dt)
      #pragma unroll
      for (int stl = 0; stl < 2; ++stl) {
        int lr = wv * 64 + stl * 32 + l31;
        #pragma unroll
        for (int q = 0; q < 4; ++q) {
          uint2 d2 = make_uint2(pk2(zacc[dt][stl][4 * q + 0], zacc[dt][stl][4 * q + 1]),
                                pk2(zacc[dt][stl][4 * q + 2], zacc[dt][stl][4 * q + 3]));
          *reinterpret_cast<uint2*>(
              sm + lr * 128 + (((dt * 4 + q) ^ (lr & 7)) << 4) + (hi << 3)) = d2;
        }
      }
  }

  // ---- phase 4: LN2(z + bf2 + y) -> out (transposed) ----
  {
    float z[64];
    #pragma unroll
    for (int c = 0; c < 8; ++c) {
      FragU zf;
      zf.f = *reinterpret_cast<const short8*>(sm + tid * 128 + ((c ^ (tid & 7)) << 4));
      #pragma unroll
      for (int u = 0; u < 4; ++u) {
        int d = c * 8 + 2 * u;
        z[d]     = lo_f(zf.w[u]) + ps[192 + d]     + lo_f(ypk[4 * c + u]);
        z[d + 1] = hi_f(zf.w[u]) + ps[192 + d + 1] + hi_f(ypk[4 * c + u]);
      }
    }
    float m0 = 0.f, m1 = 0.f, m2 = 0.f, m3 = 0.f;
    #pragma unroll
    for (int j = 0; j < 16; ++j) {
      m0 += z[4*j+0]; m1 += z[4*j+1]; m2 += z[4*j+2]; m3 += z[4*j+3];
    }
    float mu2 = ((m0 + m1) + (m2 + m3)) * (1.f / 64.f);
    float v0 = 0.f, v1 = 0.f, v2 = 0.f, v3 = 0.f;
    #pragma unroll
    for (int j = 0; j < 16; ++j) {
      float t0 = z[4*j+0] - mu2, t1 = z[4*j+1] - mu2;
      float t2 = z[4*j+2] - mu2, t3 = z[4*j+3] - mu2;
      v0 = fmaf(t0, t0, v0); v1 = fmaf(t1, t1, v1);
      v2 = fmaf(t2, t2, v2); v3 = fmaf(t3, t3, v3);
    }
    float var2 = ((v0 + v1) + (v2 + v3)) * (1.f / 64.f);
    float rs2 = rsqrtf(var2 + 1e-5f);
    float4* op = reinterpret_cast<float4*>(out + ((size_t)tid * NT + t) * DIM);
    #pragma unroll
    for (int i = 0; i < 16; ++i) {
      op[i] = make_float4(
          (z[4*i+0] - mu2) * rs2 * ps[256 + 4*i+0] + ps[320 + 4*i+0],
          (z[4*i+1] - mu2) * rs2 * ps[256 + 4*i+1] + ps[320 + 4*i+1],
          (z[4*i+2] - mu2) * rs2 * ps[256 + 4*i+2] + ps[320 + 4*i+2],
          (z[4*i+3] - mu2) * rs2 * ps[256 + 4*i+3] + ps[320 + 4*i+3]);
    }
  }
}

extern "C" void kernel_launch(void* const* d_in, const int* in_sizes, int n_in,
                              void* d_out, int out_size, void* d_ws, size_t ws_size,
                              hipStream_t stream) {
  const float* x    = (const float*)d_in[0];
  const float* Wqkv = (const float*)d_in[1];
  const float* bqkv = (const float*)d_in[2];
  const float* Wo   = (const float*)d_in[3];
  const float* bo   = (const float*)d_in[4];
  const float* g1   = (const float*)d_in[5];
  const float* be1  = (const float*)d_in[6];
  const float* W1   = (const float*)d_in[7];
  const float* bf1  = (const float*)d_in[8];
  const float* W2   = (const float*)d_in[9];
  const float* bf2  = (const float*)d_in[10];
  const float* g2   = (const float*)d_in[11];
  const float* be2  = (const float*)d_in[12];
  float* out = (float*)d_out;

  // ws: bf16 weights [0,128KB) | ctx bf16 @128KB (32MB)
  __hip_bfloat16* wb   = (__hip_bfloat16*)d_ws;
  __hip_bfloat16* ctxb = (__hip_bfloat16*)((char*)d_ws + 131072);

  hipLaunchKernelGGL(k_cvt, dim3(192), dim3(256), 0, stream, Wqkv, Wo, W1, W2, wb);
  hipLaunchKernelGGL(k_attn, dim3(NT * 2), dim3(512), 0, stream, x, wb, bqkv, ctxb);
  hipLaunchKernelGGL(k_tail, dim3(NT), dim3(512), 0, stream,
                     ctxb, x, wb + 12288, bo, g1, be1, wb + 16384, bf1,
                     wb + 32768, bf2, g2, be2, out);
}

// Round 18
// 145.840 us; speedup vs baseline: 1.0281x; 1.0281x over previous
//
#include <hip/hip_runtime.h>
#include <hip/hip_bf16.h>
#include <cmath>

#define NS 512   // n_stocks (attention sequence length)
#define NT 512   // tau (batch)
#define DIM 64
#define HD 32

typedef __attribute__((ext_vector_type(8))) short short8;    // 8 bf16 = 4 VGPR
typedef __attribute__((ext_vector_type(16))) float f32x16;   // MFMA 32x32 acc

union FragU { unsigned w[4]; short8 f; };

// 2^x. Builtin/libm form lowers to v_exp_f32 but stays visible to the
// scheduler (inline-asm version cost +23 us in rounds 4/5 — latency opaque).
#if __has_builtin(__builtin_amdgcn_exp2f)
#define EXP2F __builtin_amdgcn_exp2f
#else
#define EXP2F exp2f
#endif

// bf16 RNE rounding, bit-trick form (bit-identical to __float2bfloat16 for
// finite values; inputs are finite). Result in HIGH 16 bits.
// NOTE round 8: inline-asm v_cvt_pk_bf16_f32 produced NaN on gfx950 — never
// hand-write that instruction.
__device__ __forceinline__ unsigned bfround(float x) {
  unsigned u = __float_as_uint(x);
  return u + 0x7fffu + ((u >> 16) & 1u);
}
// pack two fp32 -> {hi16=bf16(hi), lo16=bf16(lo)} via one v_perm_b32
__device__ __forceinline__ unsigned pk2(float lo, float hi) {
  return __builtin_amdgcn_perm(bfround(hi), bfround(lo), 0x07060302u);
}
__device__ __forceinline__ float lo_f(unsigned w) { return __uint_as_float(w << 16); }
__device__ __forceinline__ float hi_f(unsigned w) { return __uint_as_float(w & 0xffff0000u); }
__device__ __forceinline__ short8 ldg8(const __hip_bfloat16* p) {
  return *reinterpret_cast<const short8*>(p);
}

// v_permlane32_swap_b32: a' = [a.lo | b.lo], b' = [a.hi | b.hi]
__device__ __forceinline__ void pl32swap(unsigned& a, unsigned& b) {
  asm volatile("v_permlane32_swap_b32 %0, %1" : "+v"(a), "+v"(b));
}

// Repack a 32x32 C-frag (col=l31, row=(r&3)+8*(r>>2)+4*hi) into two A/B-frags
// along k (o1: k=0..15, o2: k=16..31). Validated rounds 2-17.
__device__ __forceinline__ void repack(const float* p, short8& o1, short8& o2) {
  unsigned pk[8];
  #pragma unroll
  for (int j = 0; j < 8; ++j) pk[j] = pk2(p[2 * j], p[2 * j + 1]);
  pl32swap(pk[0], pk[2]);
  pl32swap(pk[1], pk[3]);
  pl32swap(pk[4], pk[6]);
  pl32swap(pk[5], pk[7]);
  FragU a1, a2;
  a1.w[0] = pk[0]; a1.w[1] = pk[1]; a1.w[2] = pk[2]; a1.w[3] = pk[3];
  a2.w[0] = pk[4]; a2.w[1] = pk[5]; a2.w[2] = pk[6]; a2.w[3] = pk[7];
  o1 = a1.f; o2 = a2.f;
}

// ---------------- K0: convert all weights fp32 -> bf16 in ws ----------------
// layout: Wqkv @0 (12288) | Wo @12288 (4096) | W1 @16384 (16384) | W2 @32768 (16384)
__global__ void k_cvt(const float* __restrict__ Wqkv, const float* __restrict__ Wo,
                      const float* __restrict__ W1, const float* __restrict__ W2,
                      __hip_bfloat16* __restrict__ dst) {
  int i = blockIdx.x * 256 + threadIdx.x;  // 49152 total
  float v;
  if (i < 12288) v = Wqkv[i];
  else if (i < 16384) v = Wo[i - 12288];
  else if (i < 32768) v = W1[i - 16384];
  else v = W2[i - 32768];
  *reinterpret_cast<unsigned short*>(dst + i) = (unsigned short)(bfround(v) >> 16);
}

// ---------------- K1: MFMA QKV projection + MFMA attention -----------------
// FINAL (round-16 validated, 146.7us total): one block per (t,h), 512 thr =
// 8 waves; T1 XCD swizzle keeps the (t,0)/(t,1) pair on one XCD so the shared
// 128KB x-read L2-hits (FETCH 85 -> 51MB). Swapped-operand QK^T (softmax
// lane-local), no-running-max softmax via exp2 with folded log2e, permlane
// repack, PV swapped so 1/l is lane-local, K/V/Q biases folded or dropped.
__global__ __launch_bounds__(512, 4) void k_attn(
    const float* __restrict__ x, const __hip_bfloat16* __restrict__ Wb,
    const float* __restrict__ bqkv, __hip_bfloat16* __restrict__ ctx) {
  __shared__ char smem[65536];
  const int bid = blockIdx.x;
  const int t = (bid & 7) | ((bid >> 4) << 3);
  const int h = (bid >> 3) & 1;
  const int tid = threadIdx.x;
  const int l = tid & 63, wv = tid >> 6, hi = l >> 5, l31 = l & 31;

  // ---- x fragments: lane row = wv*64+rt*32+l31, dims st*16+hi*8+(0..7) ----
  short8 xf[2][4];
  #pragma unroll
  for (int rt = 0; rt < 2; ++rt) {
    int row = wv * 64 + rt * 32 + l31;
    const float* xr = x + ((size_t)row * NT + t) * DIM + hi * 8;
    #pragma unroll
    for (int st = 0; st < 4; ++st) {
      float4 f0 = *reinterpret_cast<const float4*>(xr + st * 16);
      float4 f1 = *reinterpret_cast<const float4*>(xr + st * 16 + 4);
      FragU fu;
      fu.w[0] = pk2(f0.x, f0.y); fu.w[1] = pk2(f0.z, f0.w);
      fu.w[2] = pk2(f1.x, f1.y); fu.w[3] = pk2(f1.z, f1.w);
      xf[rt][st] = fu.f;
    }
  }

  // ---- K proj (transposed: C rows = kd, cols = stock) -> row-major Ksm ----
  {
    short8 wkb[4];
    #pragma unroll
    for (int st = 0; st < 4; ++st)
      wkb[st] = ldg8(Wb + (size_t)(64 + h * 32 + l31) * 64 + st * 16 + hi * 8);
    #pragma unroll
    for (int rt = 0; rt < 2; ++rt) {
      f32x16 ka = {};
      #pragma unroll
      for (int st = 0; st < 4; ++st)
        ka = __builtin_amdgcn_mfma_f32_32x32x16_bf16(wkb[st], xf[rt][st], ka, 0, 0, 0);
      int stock = wv * 64 + rt * 32 + l31;
      char* kb = smem + stock * 64 + (hi << 3);
      #pragma unroll
      for (int rq = 0; rq < 4; ++rq) {  // regs 4rq..4rq+3 -> kd = 8rq+4hi+(0..3)
        uint2 d2 = make_uint2(pk2(ka[4 * rq + 0], ka[4 * rq + 1]),
                              pk2(ka[4 * rq + 2], ka[4 * rq + 3]));
        *reinterpret_cast<uint2*>(kb + ((rq ^ ((stock >> 1) & 3)) << 4)) = d2;
      }
    }
  }

  // ---- V proj -> Vt[vd][key] (bias folded at store) ----
  {
    short8 wvb[4];
    #pragma unroll
    for (int st = 0; st < 4; ++st)
      wvb[st] = ldg8(Wb + (size_t)(128 + h * 32 + l31) * 64 + st * 16 + hi * 8);
    #pragma unroll
    for (int rt = 0; rt < 2; ++rt) {
      f32x16 va = {};
      #pragma unroll
      for (int st = 0; st < 4; ++st)
        va = __builtin_amdgcn_mfma_f32_32x32x16_bf16(xf[rt][st], wvb[st], va, 0, 0, 0);
      #pragma unroll
      for (int g = 0; g < 4; ++g) {
        int kb = wv * 64 + rt * 32 + g * 8 + hi * 4;
        uint2 d2 = make_uint2(pk2(va[4 * g + 0], va[4 * g + 1]),
                              pk2(va[4 * g + 2], va[4 * g + 3]));
        *reinterpret_cast<uint2*>(
            smem + 32768 + l31 * 1024 + (((kb >> 3) ^ (l31 & 7)) << 4) + ((kb & 7) << 1)) = d2;
      }
    }
  }

  // ---- Q^T proj -> qfrag (registers); scale = 1/sqrt(32) * log2(e) ----
  short8 qfrag[2][2];
  {
    short8 wqa[4];
    #pragma unroll
    for (int st = 0; st < 4; ++st)
      wqa[st] = ldg8(Wb + (size_t)(h * 32 + l31) * 64 + st * 16 + hi * 8);
    float bqv[16];
    #pragma unroll
    for (int r = 0; r < 16; ++r)
      bqv[r] = bqkv[h * 32 + (r & 3) + 8 * (r >> 2) + 4 * hi];
    #pragma unroll
    for (int rt = 0; rt < 2; ++rt) {
      f32x16 qa = {};
      #pragma unroll
      for (int st = 0; st < 4; ++st)
        qa = __builtin_amdgcn_mfma_f32_32x32x16_bf16(wqa[st], xf[rt][st], qa, 0, 0, 0);
      float p[16];
      #pragma unroll
      for (int r = 0; r < 16; ++r) p[r] = (qa[r] + bqv[r]) * 0.25503488921708395f;
      repack(p, qfrag[rt][0], qfrag[rt][1]);
    }
  }

  float bvv[16];  // V-bias (vd = (r&3)+8*(r>>2)+4*hi)
  #pragma unroll
  for (int r = 0; r < 16; ++r)
    bvv[r] = bqkv[128 + h * 32 + (r & 3) + 8 * (r >> 2) + 4 * hi];

  __syncthreads();

  // ---- attention main loop over 16 key tiles of 32 ----
  f32x16 oacc[2];
  #pragma unroll
  for (int i = 0; i < 16; ++i) { oacc[0][i] = 0.f; oacc[1][i] = 0.f; }
  float lsum[2] = {0.f, 0.f};

  #pragma clang loop unroll(disable)
  for (int kt = 0; kt < 16; ++kt) {
    short8 kfrag[2], vfrag[2];
    int row = kt * 32 + l31;
    #pragma unroll
    for (int dc = 0; dc < 2; ++dc)
      kfrag[dc] = *reinterpret_cast<const short8*>(
          smem + row * 64 + ((((dc << 1) | hi) ^ ((row >> 1) & 3)) << 4));
    #pragma unroll
    for (int c = 0; c < 2; ++c) {
      int ck = kt * 4 + (c << 1) + hi;
      vfrag[c] = *reinterpret_cast<const short8*>(
          smem + 32768 + l31 * 1024 + ((ck ^ (l31 & 7)) << 4));
    }
    #pragma unroll
    for (int sb = 0; sb < 2; ++sb) {
      f32x16 sC = {};
      sC = __builtin_amdgcn_mfma_f32_32x32x16_bf16(kfrag[0], qfrag[sb][0], sC, 0, 0, 0);
      sC = __builtin_amdgcn_mfma_f32_32x32x16_bf16(kfrag[1], qfrag[sb][1], sC, 0, 0, 0);
      float p[16];
      #pragma unroll
      for (int r = 0; r < 16; ++r) p[r] = EXP2F(sC[r]);
      // pairwise tree (depth 5) instead of a 16-deep serial chain
      float t0 = (p[0] + p[1]) + (p[2] + p[3]);
      float t1 = (p[4] + p[5]) + (p[6] + p[7]);
      float t2 = (p[8] + p[9]) + (p[10] + p[11]);
      float t3 = (p[12] + p[13]) + (p[14] + p[15]);
      lsum[sb] += (t0 + t1) + (t2 + t3);
      short8 a1, a2;
      repack(p, a1, a2);
      // PV swapped: C[row=vd][col=query] -> 1/l lane-local
      oacc[sb] = __builtin_amdgcn_mfma_f32_32x32x16_bf16(vfrag[0], a1, oacc[sb], 0, 0, 0);
      oacc[sb] = __builtin_amdgcn_mfma_f32_32x32x16_bf16(vfrag[1], a2, oacc[sb], 0, 0, 0);
    }
  }

  // ---- normalize (lane-local) + V-bias + uint2 stores ----
  #pragma unroll
  for (int sb = 0; sb < 2; ++sb) {
    float lt = lsum[sb] + __shfl_xor(lsum[sb], 32, 64);
    float inv = 1.f / lt;
    int q = wv * 64 + sb * 32 + l31;
    __hip_bfloat16* cb = ctx + ((size_t)t * 512 + q) * 64 + h * 32;
    #pragma unroll
    for (int g = 0; g < 4; ++g) {  // regs 4g..4g+3 -> vd = 8g+4hi+(0..3)
      uint2 d2 = make_uint2(
          pk2(fmaf(oacc[sb][4 * g + 0], inv, bvv[4 * g + 0]),
              fmaf(oacc[sb][4 * g + 1], inv, bvv[4 * g + 1])),
          pk2(fmaf(oacc[sb][4 * g + 2], inv, bvv[4 * g + 2]),
              fmaf(oacc[sb][4 * g + 3], inv, bvv[4 * g + 3])));
      *reinterpret_cast<uint2*>(cb + 8 * g + 4 * hi) = d2;
    }
  }
}

// ---------------- K2: MFMA Wo + LN1 + MFMA FFN + LN2 ----------------
// One block per t, 512 thr = 8 waves. Round-11-validated version: W1/W2
// staged to LDS (loads issued at kernel top, hidden under phase 1), ONE
// barrier, wave-private R1 dataflow ctx -> aout^T -> y -> z^T, y packed in
// regs for the LN2 residual.
__global__ __launch_bounds__(512, 2) void k_tail(
    const __hip_bfloat16* __restrict__ ctx, const float* __restrict__ x,
    const __hip_bfloat16* __restrict__ Wob,
    const float* __restrict__ bo, const float* __restrict__ g1,
    const float* __restrict__ be1, const __hip_bfloat16* __restrict__ W1b,
    const float* __restrict__ bf1, const __hip_bfloat16* __restrict__ W2b,
    const float* __restrict__ bf2, const float* __restrict__ g2,
    const float* __restrict__ be2, float* __restrict__ out) {
  __shared__ char sm[133632];
  float* ps = reinterpret_cast<float*>(sm + 131072);
  const int t = blockIdx.x;
  const int tid = threadIdx.x;
  const int l = tid & 63, wv = tid >> 6, hi = l >> 5, l31 = l & 31;

  // ---- issue weight staging loads (latency hidden under phase 1) ----
  short8 wst[8];
  {
    const short8* w1p = reinterpret_cast<const short8*>(W1b);
    const short8* w2p = reinterpret_cast<const short8*>(W2b);
    #pragma unroll
    for (int j = 0; j < 4; ++j) wst[j] = w1p[tid + 512 * j];
    #pragma unroll
    for (int j = 0; j < 4; ++j) wst[4 + j] = w2p[tid + 512 * j];
  }

  // ---- stage ctx row + params ----
  {
    const short8* cp = reinterpret_cast<const short8*>(ctx + ((size_t)t * 512 + tid) * 64);
    #pragma unroll
    for (int c = 0; c < 8; ++c)
      *reinterpret_cast<short8*>(sm + tid * 128 + ((c ^ (tid & 7)) << 4)) = cp[c];
  }
  for (int i = tid; i < 640; i += 512) {
    float v;
    if (i < 64) v = g1[i];
    else if (i < 128) v = be1[i - 64];
    else if (i < 192) v = bo[i - 128];
    else if (i < 256) v = bf2[i - 192];
    else if (i < 320) v = g2[i - 256];
    else if (i < 384) v = be2[i - 320];
    else v = bf1[i - 384];
    ps[i] = v;
  }

  // ---- phase 1: aout^T = Wo @ ctx^T, scatter into R1 (wave-private) ----
  {
    short8 cb[2][4];
    #pragma unroll
    for (int stl = 0; stl < 2; ++stl) {
      int lr = wv * 64 + stl * 32 + l31;
      #pragma unroll
      for (int st = 0; st < 4; ++st)
        cb[stl][st] = *reinterpret_cast<const short8*>(
            sm + lr * 128 + ((((st << 1) | hi) ^ (lr & 7)) << 4));
    }
    #pragma unroll
    for (int dt = 0; dt < 2; ++dt) {
      short8 wa[4];
      #pragma unroll
      for (int st = 0; st < 4; ++st)
        wa[st] = ldg8(Wob + (size_t)(dt * 32 + l31) * 64 + st * 16 + hi * 8);
      #pragma unroll
      for (int stl = 0; stl < 2; ++stl) {
        f32x16 a = {};
        #pragma unroll
        for (int st = 0; st < 4; ++st)
          a = __builtin_amdgcn_mfma_f32_32x32x16_bf16(wa[st], cb[stl][st], a, 0, 0, 0);
        int lr = wv * 64 + stl * 32 + l31;
        #pragma unroll
        for (int q = 0; q < 4; ++q) {  // regs 4q..4q+3 -> d = dt*32+8q+4hi+(0..3)
          uint2 d2 = make_uint2(pk2(a[4 * q + 0], a[4 * q + 1]),
                                pk2(a[4 * q + 2], a[4 * q + 3]));
          *reinterpret_cast<uint2*>(
              sm + lr * 128 + (((dt * 4 + q) ^ (lr & 7)) << 4) + (hi << 3)) = d2;
        }
      }
    }
  }

  // ---- write staged weights to LDS (swizzled), then the ONE barrier ----
  {
    #pragma unroll
    for (int j = 0; j < 4; ++j) {
      int g = tid + 512 * j;  // W1 [256][64]: row=g>>3, chunk=g&7
      *reinterpret_cast<short8*>(
          sm + 65536 + (g >> 3) * 128 + (((g & 7) ^ ((g >> 3) & 7)) << 4)) = wst[j];
    }
    #pragma unroll
    for (int j = 0; j < 4; ++j) {
      int g = tid + 512 * j;  // W2 [64][256]: row=g>>5, chunk=g&31
      *reinterpret_cast<short8*>(
          sm + 98304 + (g >> 5) * 512 + (((g & 31) ^ ((g >> 5) & 7)) << 4)) = wst[4 + j];
    }
  }
  __syncthreads();

  // ---- phase 2: y = LN1(x + aout + bo); y -> R1 rows + packed regs ----
  unsigned ypk[32];
  {
    float ao[64];
    #pragma unroll
    for (int c = 0; c < 8; ++c) {
      FragU fu;
      fu.f = *reinterpret_cast<const short8*>(sm + tid * 128 + ((c ^ (tid & 7)) << 4));
      #pragma unroll
      for (int u = 0; u < 4; ++u) {
        ao[c * 8 + 2 * u]     = lo_f(fu.w[u]);
        ao[c * 8 + 2 * u + 1] = hi_f(fu.w[u]);
      }
    }
    float y[64];
    const float4* xp = reinterpret_cast<const float4*>(x + ((size_t)tid * NT + t) * DIM);
    #pragma unroll
    for (int i = 0; i < 16; ++i) {
      float4 v = xp[i];
      y[4*i+0] = v.x + ao[4*i+0] + ps[128 + 4*i+0];
      y[4*i+1] = v.y + ao[4*i+1] + ps[128 + 4*i+1];
      y[4*i+2] = v.z + ao[4*i+2] + ps[128 + 4*i+2];
      y[4*i+3] = v.w + ao[4*i+3] + ps[128 + 4*i+3];
    }
    float m0 = 0.f, m1 = 0.f, m2 = 0.f, m3 = 0.f;
    #pragma unroll
    for (int j = 0; j < 16; ++j) {
      m0 += y[4*j+0]; m1 += y[4*j+1]; m2 += y[4*j+2]; m3 += y[4*j+3];
    }
    float mu = ((m0 + m1) + (m2 + m3)) * (1.f / 64.f);
    float v0 = 0.f, v1 = 0.f, v2 = 0.f, v3 = 0.f;
    #pragma unroll
    for (int j = 0; j < 16; ++j) {
      float t0 = y[4*j+0] - mu, t1 = y[4*j+1] - mu;
      float t2 = y[4*j+2] - mu, t3 = y[4*j+3] - mu;
      v0 = fmaf(t0, t0, v0); v1 = fmaf(t1, t1, v1);
      v2 = fmaf(t2, t2, v2); v3 = fmaf(t3, t3, v3);
    }
    float var = ((v0 + v1) + (v2 + v3)) * (1.f / 64.f);
    float rs = rsqrtf(var + 1e-5f);
    #pragma unroll
    for (int d = 0; d < 64; ++d) y[d] = (y[d] - mu) * rs * ps[d] + ps[64 + d];
    #pragma unroll
    for (int c = 0; c < 8; ++c) {
      FragU fu;
      #pragma unroll
      for (int u = 0; u < 4; ++u) {
        fu.w[u] = pk2(y[c*8 + 2*u], y[c*8 + 2*u + 1]);
        ypk[4 * c + u] = fu.w[u];
      }
      *reinterpret_cast<short8*>(sm + tid * 128 + ((c ^ (tid & 7)) << 4)) = fu.f;
    }
  }

  // ---- phase 3: FFN, jt-outer (weights once, from LDS); z^T -> R1 ----
  {
    short8 yb[2][4];
    #pragma unroll
    for (int stl = 0; stl < 2; ++stl) {
      int lr = wv * 64 + stl * 32 + l31;
      #pragma unroll
      for (int st = 0; st < 4; ++st)
        yb[stl][st] = *reinterpret_cast<const short8*>(
            sm + lr * 128 + ((((st << 1) | hi) ^ (lr & 7)) << 4));
    }
    f32x16 zacc[2][2];
    #pragma unroll
    for (int i = 0; i < 16; ++i) {
      zacc[0][0][i] = 0.f; zacc[0][1][i] = 0.f; zacc[1][0][i] = 0.f; zacc[1][1][i] = 0.f;
    }
    #pragma clang loop unroll_count(2)
    for (int jt = 0; jt < 8; ++jt) {
      short8 w1a[4];
      #pragma unroll
      for (int st = 0; st < 4; ++st) {
        int row = jt * 32 + l31, c1 = (st << 1) | hi;
        w1a[st] = *reinterpret_cast<const short8*>(
            sm + 65536 + row * 128 + ((c1 ^ (row & 7)) << 4));
      }
      short8 w2f[2][2];
      #pragma unroll
      for (int dt = 0; dt < 2; ++dt)
        #pragma unroll
        for (int ks = 0; ks < 2; ++ks) {
          int row = dt * 32 + l31, c2 = jt * 4 + ks * 2 + hi;
          w2f[dt][ks] = *reinterpret_cast<const short8*>(
              sm + 98304 + row * 512 + ((c2 ^ (row & 7)) << 4));
        }
      float b1v[16];
      #pragma unroll
      for (int r = 0; r < 16; ++r)
        b1v[r] = ps[384 + jt * 32 + (r & 3) + 8 * (r >> 2) + 4 * hi];
      #pragma unroll
      for (int stl = 0; stl < 2; ++stl) {
        f32x16 ha = {};
        #pragma unroll
        for (int st = 0; st < 4; ++st)
          ha = __builtin_amdgcn_mfma_f32_32x32x16_bf16(w1a[st], yb[stl][st], ha, 0, 0, 0);
        float p[16];
        #pragma unroll
        for (int r = 0; r < 16; ++r) p[r] = fmaxf(ha[r] + b1v[r], 0.f);
        short8 b1, b2;
        repack(p, b1, b2);
        zacc[0][stl] = __builtin_amdgcn_mfma_f32_32x32x16_bf16(w2f[0][0], b1, zacc[0][stl], 0, 0, 0);
        zacc[0][stl] = __builtin_amdgcn_mfma_f32_32x32x16_bf16(w2f[0][1], b2, zacc[0][stl], 0, 0, 0);
        zacc[1][stl] = __builtin_amdgcn_mfma_f32_32x32x16_bf16(w2f[1][0], b1, zacc[1][stl], 0, 0, 0);
        zacc[1][stl] = __builtin_amdgcn_mfma_f32_32x32x16_bf16(w2f[1][1], b2, zacc[1][stl], 0, 0, 0);
      }
    }
    #pragma unroll
    for (int dt = 0; dt < 2; ++dt)
      #pragma unroll
      for (int stl = 0; stl < 2; ++stl) {
        int lr = wv * 64 + stl * 32 + l31;
        #pragma unroll
        for (int q = 0; q < 4; ++q) {
          uint2 d2 = make_uint2(pk2(zacc[dt][stl][4 * q + 0], zacc[dt][stl][4 * q + 1]),
                                pk2(zacc[dt][stl][4 * q + 2], zacc[dt][stl][4 * q + 3]));
          *reinterpret_cast<uint2*>(
              sm + lr * 128 + (((dt * 4 + q) ^ (lr & 7)) << 4) + (hi << 3)) = d2;
        }
      }
  }

  // ---- phase 4: LN2(z + bf2 + y) -> out (transposed) ----
  {
    float z[64];
    #pragma unroll
    for (int c = 0; c < 8; ++c) {
      FragU zf;
      zf.f = *reinterpret_cast<const short8*>(sm + tid * 128 + ((c ^ (tid & 7)) << 4));
      #pragma unroll
      for (int u = 0; u < 4; ++u) {
        int d = c * 8 + 2 * u;
        z[d]     = lo_f(zf.w[u]) + ps[192 + d]     + lo_f(ypk[4 * c + u]);
        z[d + 1] = hi_f(zf.w[u]) + ps[192 + d + 1] + hi_f(ypk[4 * c + u]);
      }
    }
    float m0 = 0.f, m1 = 0.f, m2 = 0.f, m3 = 0.f;
    #pragma unroll
    for (int j = 0; j < 16; ++j) {
      m0 += z[4*j+0]; m1 += z[4*j+1]; m2 += z[4*j+2]; m3 += z[4*j+3];
    }
    float mu2 = ((m0 + m1) + (m2 + m3)) * (1.f / 64.f);
    float v0 = 0.f, v1 = 0.f, v2 = 0.f, v3 = 0.f;
    #pragma unroll
    for (int j = 0; j < 16; ++j) {
      float t0 = z[4*j+0] - mu2, t1 = z[4*j+1] - mu2;
      float t2 = z[4*j+2] - mu2, t3 = z[4*j+3] - mu2;
      v0 = fmaf(t0, t0, v0); v1 = fmaf(t1, t1, v1);
      v2 = fmaf(t2, t2, v2); v3 = fmaf(t3, t3, v3);
    }
    float var2 = ((v0 + v1) + (v2 + v3)) * (1.f / 64.f);
    float rs2 = rsqrtf(var2 + 1e-5f);
    float4* op = reinterpret_cast<float4*>(out + ((size_t)tid * NT + t) * DIM);
    #pragma unroll
    for (int i = 0; i < 16; ++i) {
      op[i] = make_float4(
          (z[4*i+0] - mu2) * rs2 * ps[256 + 4*i+0] + ps[320 + 4*i+0],
          (z[4*i+1] - mu2) * rs2 * ps[256 + 4*i+1] + ps[320 + 4*i+1],
          (z[4*i+2] - mu2) * rs2 * ps[256 + 4*i+2] + ps[320 + 4*i+2],
          (z[4*i+3] - mu2) * rs2 * ps[256 + 4*i+3] + ps[320 + 4*i+3]);
    }
  }
}

extern "C" void kernel_launch(void* const* d_in, const int* in_sizes, int n_in,
                              void* d_out, int out_size, void* d_ws, size_t ws_size,
                              hipStream_t stream) {
  const float* x    = (const float*)d_in[0];
  const float* Wqkv = (const float*)d_in[1];
  const float* bqkv = (const float*)d_in[2];
  const float* Wo   = (const float*)d_in[3];
  const float* bo   = (const float*)d_in[4];
  const float* g1   = (const float*)d_in[5];
  const float* be1  = (const float*)d_in[6];
  const float* W1   = (const float*)d_in[7];
  const float* bf1  = (const float*)d_in[8];
  const float* W2   = (const float*)d_in[9];
  const float* bf2  = (const float*)d_in[10];
  const float* g2   = (const float*)d_in[11];
  const float* be2  = (const float*)d_in[12];
  float* out = (float*)d_out;

  // ws: bf16 weights [0,128KB) | ctx bf16 @128KB (32MB)
  __hip_bfloat16* wb   = (__hip_bfloat16*)d_ws;
  __hip_bfloat16* ctxb = (__hip_bfloat16*)((char*)d_ws + 131072);

  hipLaunchKernelGGL(k_cvt, dim3(192), dim3(256), 0, stream, Wqkv, Wo, W1, W2, wb);
  hipLaunchKernelGGL(k_attn, dim3(NT * 2), dim3(512), 0, stream, x, wb, bqkv, ctxb);
  hipLaunchKernelGGL(k_tail, dim3(NT), dim3(512), 0, stream,
                     ctxb, x, wb + 12288, bo, g1, be1, wb + 16384, bf1,
                     wb + 32768, bf2, g2, be2, out);
}